// Round 14
// baseline (166.104 us; speedup 1.0000x reference)
//
#include <hip/hip_runtime.h>

// GAE + FiLM, fully fused; single-round grid (256 blocks = 1/CU), each block
// serially processes SEGS=4 segments with NO barrier between seg-s film phase
// and seg-(s+1) load phase (thread-owned LDS slots -> in-order per thread).
// Dims fixed by setup_inputs(): N=2e6, Z=32, H=64, B=1024. batch_vec sorted.
#define ZDIM 32
#define HDIM 64
#define BGRAPH 1024
#define CAP 2030            // nodes cached in LDS (129,920 B dynamic)
#define NTHREADS 1024
#define SEGS 4              // segments per block; grid = BGRAPH/SEGS = 256

typedef float f4 __attribute__((ext_vector_type(4)));
typedef unsigned short u16x4 __attribute__((ext_vector_type(4)));   // 8B bf16 quad

__device__ __forceinline__ unsigned short f2bf(float f) {
    unsigned int u = __float_as_uint(f);
    return (unsigned short)((u + 0x7FFFu + ((u >> 16) & 1u)) >> 16);
}
__device__ __forceinline__ float bf2f(unsigned short h) {
    return __uint_as_float(((unsigned int)h) << 16);
}

// ---------------------------------------------------------------------------
// bounds[b] = first node index with bvec[i] >= b; bounds[B] = N. (~2us.)
// ---------------------------------------------------------------------------
__global__ __launch_bounds__(256) void k_bounds(
    const int* __restrict__ bvec, int* __restrict__ bounds, int N)
{
    const long i = (long)blockIdx.x * 256 + threadIdx.x;
    if (i >= N) return;
    const int cur = bvec[i];
    if (i == 0) {
        for (int b = 0; b <= cur; ++b) bounds[b] = 0;
    } else {
        const int prev = bvec[i - 1];
        for (int b = prev + 1; b <= cur; ++b) bounds[b] = (int)i;
    }
    if (i == N - 1) {
        for (int b = cur + 1; b <= BGRAPH; ++b) bounds[b] = N;
    }
}

// ---------------------------------------------------------------------------
__global__ __launch_bounds__(NTHREADS) void k_fused(
    const float* __restrict__ z, const int* __restrict__ bounds,
    const float* __restrict__ Wg, const float* __restrict__ bgp,
    const float* __restrict__ W1, const float* __restrict__ b1,
    const float* __restrict__ W2, const float* __restrict__ b2,
    float* __restrict__ out, float* __restrict__ g_out)
{
    extern __shared__ u16x4 z16s[];                 // CAP*8 entries, 8B each
    __shared__ float accum[1 + ZDIM];               // [denom | weighted sums]
    __shared__ float gsh[ZDIM];
    __shared__ float hsh[HDIM];
    __shared__ __align__(16) float fbsh[2 * ZDIM];  // [1+gamma | beta]

    const int tid  = threadIdx.x;
    const int lane = tid & 63;
    const int q    = tid & 7;                       // float4 slot within node

    if (tid < 1 + ZDIM) accum[tid] = 0.f;           // zero for segment 0
    __syncthreads();

    const f4* z4  = (const f4*)z;
    const f4  wgq = ((const f4*)Wg)[q];
    const float bg0 = bgp[0];
    f4* out4 = (f4*)out;

#define GA_PROC(zz, kk)                                                     \
    {                                                                       \
        float p = (zz).x * wgq.x + (zz).y * wgq.y +                         \
                  (zz).z * wgq.z + (zz).w * wgq.w;                          \
        p += __shfl_xor(p, 1);                                              \
        p += __shfl_xor(p, 2);                                              \
        p += __shfl_xor(p, 4);                                              \
        const float e = __expf(p + bg0);                                    \
        acc.x = fmaf(e, (zz).x, acc.x);                                     \
        acc.y = fmaf(e, (zz).y, acc.y);                                     \
        acc.z = fmaf(e, (zz).z, acc.z);                                     \
        acc.w = fmaf(e, (zz).w, acc.w);                                     \
        if (q == 0) acc_e += e;                                             \
    }
#define GA_STASH(zz, kk)                                                    \
    if ((kk) < CAP * 8) {                                                   \
        u16x4 h;                                                            \
        h.x = f2bf((zz).x); h.y = f2bf((zz).y);                             \
        h.z = f2bf((zz).z); h.w = f2bf((zz).w);                             \
        z16s[kk] = h;                                                       \
    }

    for (int si = 0; si < SEGS; ++si) {
        const int seg = blockIdx.x * SEGS + si;
        const int s0  = bounds[seg];                // L2-hot 4KB table
        const int s1  = bounds[seg + 1];
        const int nf4 = (s1 - s0) * 8;              // multiple of 8
        const long base4 = (long)s0 * 8;

        // ---- phase 1: stream + stash + accumulate (unroll x4) ----------
        // (No barrier before this: LDS slot k is owned by thread k%1024 in
        //  both the previous film phase (read) and here (write); per-thread
        //  DS ops are in-order, so read-before-overwrite holds.)
        f4 acc; acc.x = acc.y = acc.z = acc.w = 0.f;
        float acc_e = 0.f;
        {
            int k = tid;
            for (; k + 3 * NTHREADS < nf4; k += 4 * NTHREADS) {
                const f4 a0 = z4[base4 + k];
                const f4 a1 = z4[base4 + k + 1 * NTHREADS];
                const f4 a2 = z4[base4 + k + 2 * NTHREADS];
                const f4 a3 = z4[base4 + k + 3 * NTHREADS];
                GA_STASH(a0, k);                GA_PROC(a0, k);
                GA_STASH(a1, k + 1 * NTHREADS); GA_PROC(a1, k + 1 * NTHREADS);
                GA_STASH(a2, k + 2 * NTHREADS); GA_PROC(a2, k + 2 * NTHREADS);
                GA_STASH(a3, k + 3 * NTHREADS); GA_PROC(a3, k + 3 * NTHREADS);
            }
            for (; k < nf4; k += NTHREADS) {
                const f4 a0 = z4[base4 + k];
                GA_STASH(a0, k);
                GA_PROC(a0, k);
            }
        }
#pragma unroll
        for (int d = 8; d < 64; d <<= 1) {          // fold 8 node-groups/wave
            acc.x += __shfl_down(acc.x, d);
            acc.y += __shfl_down(acc.y, d);
            acc.z += __shfl_down(acc.z, d);
            acc.w += __shfl_down(acc.w, d);
            acc_e += __shfl_down(acc_e, d);
        }
        if (lane < 8) {                             // accum zeroed+barrier'd earlier
            atomicAdd(&accum[1 + q * 4 + 0], acc.x);
            atomicAdd(&accum[1 + q * 4 + 1], acc.y);
            atomicAdd(&accum[1 + q * 4 + 2], acc.z);
            atomicAdd(&accum[1 + q * 4 + 3], acc.w);
            if (lane == 0) atomicAdd(&accum[0], acc_e);
        }
        __syncthreads();

        // ---- phase 2: in-block MLP --------------------------------------
        if (tid < ZDIM) {
            const float dd = accum[0];
            const float gv = (dd > 0.f) ? accum[1 + tid] / dd : 0.f;
            gsh[tid] = gv;
            g_out[seg * ZDIM + tid] = gv;
        }
        __syncthreads();
        if (tid < HDIM) {
            float hv = b1[tid];
#pragma unroll
            for (int kk = 0; kk < ZDIM; ++kk) hv = fmaf(gsh[kk], W1[kk * HDIM + tid], hv);
            hsh[tid] = fmaxf(hv, 0.f);
        } else if (tid >= HDIM && tid < HDIM + 1 + ZDIM) {
            accum[tid - HDIM] = 0.f;                // re-zero for next segment
        }
        __syncthreads();
        if (tid < 2 * ZDIM) {
            float o = b2[tid];
#pragma unroll
            for (int h = 0; h < HDIM; ++h) o = fmaf(hsh[h], W2[h * (2 * ZDIM) + tid], o);
            fbsh[tid] = (tid < ZDIM) ? 1.0f + o : o;    // (1+gamma) | beta
        }
        __syncthreads();

        // ---- phase 3: FiLM from LDS, NT stores; NO trailing barrier -----
        const f4 ga = ((const f4*)fbsh)[q];
        const f4 be = ((const f4*)fbsh)[8 + q];
        for (int k = tid; k < nf4; k += NTHREADS) {
            f4 zz;
            if (k < CAP * 8) {
                u16x4 h = z16s[k];
                zz.x = bf2f(h.x); zz.y = bf2f(h.y);
                zz.z = bf2f(h.z); zz.w = bf2f(h.w);
            } else {
                zz = z4[base4 + k];                 // rare spill: seg > CAP nodes
            }
            f4 r;
            r.x = fmaf(zz.x, ga.x, be.x);
            r.y = fmaf(zz.y, ga.y, be.y);
            r.z = fmaf(zz.z, ga.z, be.z);
            r.w = fmaf(zz.w, ga.w, be.w);
            __builtin_nontemporal_store(r, &out4[base4 + k]);
        }
        // fbsh/ga/be captured in registers; next iteration's first write to
        // fbsh is behind 4 barriers, and z16s overwrite is thread-local.
    }
#undef GA_PROC
#undef GA_STASH
}

// ---------------------------------------------------------------------------
extern "C" void kernel_launch(void* const* d_in, const int* in_sizes, int n_in,
                              void* d_out, int out_size, void* d_ws, size_t ws_size,
                              hipStream_t stream) {
    const float* z    = (const float*)d_in[0];
    const float* Wg   = (const float*)d_in[1];
    const float* bg   = (const float*)d_in[2];
    const float* W1   = (const float*)d_in[3];
    const float* b1   = (const float*)d_in[4];
    const float* W2   = (const float*)d_in[5];
    const float* b2   = (const float*)d_in[6];
    const int*   bvec = (const int*)d_in[7];
    const int N = in_sizes[7];

    int*   bounds = (int*)d_ws;                     // B+1 ints (4.1 KB)
    float* out    = (float*)d_out;
    float* g_out  = out + (size_t)N * ZDIM;         // g after z_mod

    const int gridB = (N + 255) / 256;
    k_bounds<<<gridB, 256, 0, stream>>>(bvec, bounds, N);

    const size_t lds_bytes = (size_t)CAP * 8 * sizeof(u16x4);   // 129,920 B
    k_fused<<<BGRAPH / SEGS, NTHREADS, lds_bytes, stream>>>(
        z, bounds, Wg, bg, W1, b1, W2, b2, out, g_out);
}

// Round 15
// 93.053 us; speedup vs baseline: 1.7851x; 1.7851x over previous
//
#include <hip/hip_runtime.h>

// GAE + FiLM, fully fused: one workgroup per graph segment (R12 exact revert —
// session best at 96.8us). Unroll-4 load clause in phase 1, bf16 LDS stash,
// NT stores, precomputed bounds table.
// Dims fixed by setup_inputs(): N=2e6, Z=32, H=64, B=1024. batch_vec sorted.
#define ZDIM 32
#define HDIM 64
#define BGRAPH 1024
#define CAP 2030            // nodes cached in LDS (129,920 B dynamic; seg max ~2100, overflow spills to global)
#define NTHREADS 1024

typedef float f4 __attribute__((ext_vector_type(4)));
typedef unsigned short u16x4 __attribute__((ext_vector_type(4)));   // 8B bf16 quad

// f32 -> bf16 round-to-nearest-even (inputs are finite normals)
__device__ __forceinline__ unsigned short f2bf(float f) {
    unsigned int u = __float_as_uint(f);
    return (unsigned short)((u + 0x7FFFu + ((u >> 16) & 1u)) >> 16);
}
__device__ __forceinline__ float bf2f(unsigned short h) {
    return __uint_as_float(((unsigned int)h) << 16);
}

// ---------------------------------------------------------------------------
// bounds[b] = first node index with bvec[i] >= b, for b in [0,B]; bounds[B]=N.
// Neighbor-compare on sorted batch_vec; handles empty segments. (~2us.)
// ---------------------------------------------------------------------------
__global__ __launch_bounds__(256) void k_bounds(
    const int* __restrict__ bvec, int* __restrict__ bounds, int N)
{
    const long i = (long)blockIdx.x * 256 + threadIdx.x;
    if (i >= N) return;
    const int cur = bvec[i];
    if (i == 0) {
        for (int b = 0; b <= cur; ++b) bounds[b] = 0;
    } else {
        const int prev = bvec[i - 1];
        for (int b = prev + 1; b <= cur; ++b) bounds[b] = (int)i;
    }
    if (i == N - 1) {
        for (int b = cur + 1; b <= BGRAPH; ++b) bounds[b] = N;
    }
}

// ---------------------------------------------------------------------------
// Per block b:
//  phase 1: stream segment-b's z (f32, ONCE from HBM); main loop unrolled x4
//           (4 independent 16B loads per clause). 8 lanes/node: gate dot +
//           3-step shfl_xor; e = exp(gate); accumulate (e, e*z); stash bf16
//           z in LDS.
//  reduce:  shfl_down folds 8 node-groups/wave; LDS f32 atomics fold waves.
//  phase 2: in-block MLP; fbsh = [1+gamma | beta]; g -> out tail.
//  phase 3: replay z from LDS (bf16; err <= |z|*2^-9 ~ 0.011 << 0.129),
//           z_mod = z*(1+gamma)+beta, NT stores (worth ~30us: R6->R7 A/B;
//           read/write phase separation is essential: R13/R14 A/Bs).
// ---------------------------------------------------------------------------
__global__ __launch_bounds__(NTHREADS) void k_fused(
    const float* __restrict__ z, const int* __restrict__ bounds,
    const float* __restrict__ Wg, const float* __restrict__ bgp,
    const float* __restrict__ W1, const float* __restrict__ b1,
    const float* __restrict__ W2, const float* __restrict__ b2,
    float* __restrict__ out, float* __restrict__ g_out)
{
    extern __shared__ u16x4 z16s[];                 // CAP*8 entries, 8B each
    __shared__ float accum[1 + ZDIM];               // [denom | weighted sums]
    __shared__ float gsh[ZDIM];
    __shared__ float hsh[HDIM];
    __shared__ __align__(16) float fbsh[2 * ZDIM];  // [1+gamma | beta]

    const int b    = blockIdx.x;
    const int tid  = threadIdx.x;
    const int lane = tid & 63;
    const int q    = tid & 7;                       // float4 slot within node

    if (tid < 1 + ZDIM) accum[tid] = 0.f;
    __syncthreads();

    const int  s     = bounds[b];                   // L2-hot 4KB table
    const int  e_nd  = bounds[b + 1];
    const int  nf4   = (e_nd - s) * 8;              // float4 count, multiple of 8
    const long base4 = (long)s * 8;

    const f4* z4  = (const f4*)z;
    const f4  wgq = ((const f4*)Wg)[q];
    const float bg0 = bgp[0];

    // ---- phase 1: gate + accumulate + LDS stash (unroll x4) -------------
    f4 acc; acc.x = acc.y = acc.z = acc.w = 0.f;
    float acc_e = 0.f;

#define GA_PROC(zz, kk)                                                     \
    {                                                                       \
        if ((kk) < CAP * 8) {                                               \
            u16x4 h;                                                        \
            h.x = f2bf((zz).x); h.y = f2bf((zz).y);                         \
            h.z = f2bf((zz).z); h.w = f2bf((zz).w);                         \
            z16s[kk] = h;                                                   \
        }                                                                   \
        float p = (zz).x * wgq.x + (zz).y * wgq.y +                         \
                  (zz).z * wgq.z + (zz).w * wgq.w;                          \
        p += __shfl_xor(p, 1);                                              \
        p += __shfl_xor(p, 2);                                              \
        p += __shfl_xor(p, 4);                                              \
        const float e = __expf(p + bg0);                                    \
        acc.x = fmaf(e, (zz).x, acc.x);                                     \
        acc.y = fmaf(e, (zz).y, acc.y);                                     \
        acc.z = fmaf(e, (zz).z, acc.z);                                     \
        acc.w = fmaf(e, (zz).w, acc.w);                                     \
        if (q == 0) acc_e += e;                                             \
    }

    int k = tid;
    for (; k + 3 * NTHREADS < nf4; k += 4 * NTHREADS) {
        const f4 a0 = z4[base4 + k];
        const f4 a1 = z4[base4 + k + 1 * NTHREADS];
        const f4 a2 = z4[base4 + k + 2 * NTHREADS];
        const f4 a3 = z4[base4 + k + 3 * NTHREADS];
        GA_PROC(a0, k);
        GA_PROC(a1, k + 1 * NTHREADS);
        GA_PROC(a2, k + 2 * NTHREADS);
        GA_PROC(a3, k + 3 * NTHREADS);
    }
    for (; k < nf4; k += NTHREADS) {
        const f4 a0 = z4[base4 + k];
        GA_PROC(a0, k);
    }
#undef GA_PROC

#pragma unroll
    for (int d = 8; d < 64; d <<= 1) {              // fold 8 node-groups per wave
        acc.x += __shfl_down(acc.x, d);
        acc.y += __shfl_down(acc.y, d);
        acc.z += __shfl_down(acc.z, d);
        acc.w += __shfl_down(acc.w, d);
        acc_e += __shfl_down(acc_e, d);
    }
    if (lane < 8) {                                 // fold 16 waves via LDS atomics
        atomicAdd(&accum[1 + q * 4 + 0], acc.x);
        atomicAdd(&accum[1 + q * 4 + 1], acc.y);
        atomicAdd(&accum[1 + q * 4 + 2], acc.z);
        atomicAdd(&accum[1 + q * 4 + 3], acc.w);
        if (lane == 0) atomicAdd(&accum[0], acc_e);
    }
    __syncthreads();

    // ---- phase 2: in-block MLP ------------------------------------------
    if (tid < ZDIM) {
        const float dd = accum[0];
        const float gv = (dd > 0.f) ? accum[1 + tid] / dd : 0.f;
        gsh[tid] = gv;
        g_out[b * ZDIM + tid] = gv;
    }
    __syncthreads();
    if (tid < HDIM) {
        float hv = b1[tid];
#pragma unroll
        for (int kk = 0; kk < ZDIM; ++kk) hv = fmaf(gsh[kk], W1[kk * HDIM + tid], hv);
        hsh[tid] = fmaxf(hv, 0.f);
    }
    __syncthreads();
    if (tid < 2 * ZDIM) {
        float o = b2[tid];
#pragma unroll
        for (int h = 0; h < HDIM; ++h) o = fmaf(hsh[h], W2[h * (2 * ZDIM) + tid], o);
        fbsh[tid] = (tid < ZDIM) ? 1.0f + o : o;    // gamma stored as (1+gamma)
    }
    __syncthreads();

    // ---- phase 3: FiLM from LDS, NT stores ------------------------------
    const f4 ga = ((const f4*)fbsh)[q];
    const f4 be = ((const f4*)fbsh)[8 + q];
    f4* out4 = (f4*)out;
    for (int kk = tid; kk < nf4; kk += NTHREADS) {
        f4 zz;
        if (kk < CAP * 8) {
            u16x4 h = z16s[kk];
            zz.x = bf2f(h.x); zz.y = bf2f(h.y); zz.z = bf2f(h.z); zz.w = bf2f(h.w);
        } else {
            zz = z4[base4 + kk];                    // rare spill: seg > CAP nodes
        }
        f4 r;
        r.x = fmaf(zz.x, ga.x, be.x);
        r.y = fmaf(zz.y, ga.y, be.y);
        r.z = fmaf(zz.z, ga.z, be.z);
        r.w = fmaf(zz.w, ga.w, be.w);
        __builtin_nontemporal_store(r, &out4[base4 + kk]);
    }
}

// ---------------------------------------------------------------------------
extern "C" void kernel_launch(void* const* d_in, const int* in_sizes, int n_in,
                              void* d_out, int out_size, void* d_ws, size_t ws_size,
                              hipStream_t stream) {
    const float* z    = (const float*)d_in[0];
    const float* Wg   = (const float*)d_in[1];
    const float* bg   = (const float*)d_in[2];
    const float* W1   = (const float*)d_in[3];
    const float* b1   = (const float*)d_in[4];
    const float* W2   = (const float*)d_in[5];
    const float* b2   = (const float*)d_in[6];
    const int*   bvec = (const int*)d_in[7];
    const int N = in_sizes[7];

    int*   bounds = (int*)d_ws;                     // B+1 ints (4.1 KB)
    float* out    = (float*)d_out;
    float* g_out  = out + (size_t)N * ZDIM;         // g after z_mod

    const int gridB = (N + 255) / 256;
    k_bounds<<<gridB, 256, 0, stream>>>(bvec, bounds, N);

    const size_t lds_bytes = (size_t)CAP * 8 * sizeof(u16x4);   // 129,920 B
    k_fused<<<BGRAPH, NTHREADS, lds_bytes, stream>>>(
        z, bounds, Wg, bg, W1, b1, W2, b2, out, g_out);
}